// Round 6
// baseline (1050.219 us; speedup 1.0000x reference)
//
#include <hip/hip_runtime.h>
#include <hip/hip_bf16.h>

typedef __attribute__((ext_vector_type(8))) short bf16x8;
typedef __attribute__((ext_vector_type(4))) float f32x4;
typedef __attribute__((ext_vector_type(4))) float fvec4;
typedef __attribute__((ext_vector_type(4))) unsigned int u32x4;
typedef unsigned short u16;
typedef unsigned int u32;
typedef unsigned long long u64;

#define N_TOK 131072

// v_cvt_pk_bf16_f32: dst[15:0]=bf16(lo), dst[31:16]=bf16(hi), RNE
__device__ __forceinline__ u32 cvtpk(float lo, float hi) {
  u32 r; asm("v_cvt_pk_bf16_f32 %0, %1, %2" : "=v"(r) : "v"(lo), "v"(hi)); return r;
}
__device__ __forceinline__ u16 f2bf(float f) { return (u16)cvtpk(f, f); }

__device__ __forceinline__ f32x4 mfma16(bf16x8 a, bf16x8 b, f32x4 c) {
  return __builtin_amdgcn_mfma_f32_16x16x32_bf16(a, b, c, 0, 0, 0);
}

// swizzled index into [rows][128 shorts] LDS tile: 16B-chunk XOR row&15
__device__ __forceinline__ int tix(int row, int s) {
  return (row << 7) + ((((s >> 3) ^ (row & 15))) << 3) + (s & 7);
}
// swizzled index into [rows][64 shorts] LDS tile: 16B-chunk XOR row&7
__device__ __forceinline__ int tix64(int row, int s) {
  return (row << 6) + ((((s >> 3) ^ (row & 7))) << 3) + (s & 7);
}

// ---------------------------------------------------------------------------
// Weight prep (R1-verified): bf16 + transpose + qkv de-interleave. Linear.
//  WqT [384][128]  (row c = which*128+e, k inner)
//  WpT [128][128]  (row = out col, k inner)
//  W1T [512][128]  (row = h col, k inner)
//  W2T [128][512]  (row = out col, k inner)
// ---------------------------------------------------------------------------
__global__ __launch_bounds__(256) void prep_kernel(
    const float* __restrict__ Wqkv, const float* __restrict__ bqkv,
    const float* __restrict__ Wproj, const float* __restrict__ W1,
    const float* __restrict__ W2,
    u16* __restrict__ WqT, u16* __restrict__ WpT,
    u16* __restrict__ W1T, u16* __restrict__ W2T,
    float* __restrict__ bqp)
{
  const int idx = blockIdx.x * 256 + threadIdx.x;
  const int PER = 196608;
  if (idx < 3 * PER) {
    const int d = idx / PER, r = idx % PER;
    if (r < 49152) {                       // WqT
      const int c = r >> 7, k = r & 127;
      WqT[d * 49152 + r] = f2bf(Wqkv[(size_t)d * 49152 + k * 384 + ((c & 127) * 3 + (c >> 7))]);
    } else if (r < 65536) {                // WpT
      const int r2 = r - 49152; const int c = r2 >> 7, k = r2 & 127;
      WpT[d * 16384 + r2] = f2bf(Wproj[(size_t)d * 16384 + k * 128 + c]);
    } else if (r < 131072) {               // W1T
      const int r3 = r - 65536; const int c = r3 >> 7, k = r3 & 127;
      W1T[d * 65536 + r3] = f2bf(W1[(size_t)d * 65536 + k * 512 + c]);
    } else {                               // W2T
      const int r4 = r - 131072; const int c = r4 >> 9, k = r4 & 511;
      W2T[d * 65536 + r4] = f2bf(W2[(size_t)d * 65536 + k * 128 + c]);
    }
  } else if (idx < 3 * PER + 1152) {
    const int i2 = idx - 3 * PER; const int d = i2 / 384, c = i2 % 384;
    bqp[i2] = bqkv[d * 384 + (c & 127) * 3 + (c >> 7)];
  }
}

// ---------------------------------------------------------------------------
// img [128][131072] f32 -> x [131072][128] f32, LN1-layer0 stats -> partials
// ---------------------------------------------------------------------------
__global__ __launch_bounds__(256) void tin_kernel(const float* __restrict__ img,
                                                  float* __restrict__ x,
                                                  float* __restrict__ partials,
                                                  int prow0)
{
  __shared__ float t[128 * 65];
  __shared__ float ssum[256], sqq[256];
  const int t0 = blockIdx.x * 64;
  const int tid = threadIdx.x;
  {
    const int j = tid & 63, cq = tid >> 6;
    for (int c = cq; c < 128; c += 4) t[c * 65 + j] = img[(size_t)c * N_TOK + t0 + j];
  }
  __syncthreads();
  {
    const int c = tid & 127, jh = tid >> 7;
    float s = 0.f, q = 0.f;
    for (int jj = jh; jj < 64; jj += 2) {
      const float v = t[c * 65 + jj];
      x[(size_t)(t0 + jj) * 128 + c] = v;
      s += v; q += v * v;
    }
    ssum[tid] = s; sqq[tid] = q;
  }
  __syncthreads();
  if (tid < 128) {
    float* pr = partials + (size_t)(prow0 + blockIdx.x) * 256;
    pr[tid] = ssum[tid] + ssum[tid + 128];
    pr[128 + tid] = sqq[tid] + sqq[tid + 128];
  }
}

// x [131072][128] -> out [128][131072] with relu
__global__ __launch_bounds__(256) void tout_kernel(const float* __restrict__ x,
                                                   float* __restrict__ out)
{
  __shared__ float t[128 * 65];
  const int t0 = blockIdx.x * 64;
  const int tid = threadIdx.x;
  {
    const int c = tid & 127, jh = tid >> 7;
    for (int jj = jh; jj < 64; jj += 2) t[c * 65 + jj] = x[(size_t)(t0 + jj) * 128 + c];
  }
  __syncthreads();
  {
    const int j = tid & 63, cq = tid >> 6;
    for (int c = cq; c < 128; c += 4)
      out[(size_t)c * N_TOK + t0 + j] = fmaxf(t[c * 65 + j], 0.f);
  }
}

// stage-1 reduce: block b sums its chunk of partial rows (coalesced)
__global__ __launch_bounds__(256) void reduce1_kernel(const float* __restrict__ p,
                                                      int rows0, int nrows,
                                                      float* __restrict__ bred)
{
  const int chunk = nrows >> 6;
  const float* base = p + (size_t)(rows0 + blockIdx.x * chunk) * 256;
  float s = 0.f;
  for (int r = 0; r < chunk; ++r) s += base[r * 256 + threadIdx.x];
  bred[blockIdx.x * 256 + threadIdx.x] = s;
}

__global__ void finalize_kernel(const float* __restrict__ bred, const float* __restrict__ g,
                                const float* __restrict__ b, float* __restrict__ st)
{
  const int c = threadIdx.x;   // 128
  float s = 0.f, q = 0.f;
  for (int r = 0; r < 64; ++r) { s += bred[r * 256 + c]; q += bred[r * 256 + 128 + c]; }
  const float inv = 1.f / 131072.f;
  const float mu = s * inv;
  const float var = q * inv - mu * mu;
  const float sc = g[c] * rsqrtf(var + 1e-5f);
  st[c] = sc;
  st[128 + c] = b[c] - mu * sc;
}

// ---------------------------------------------------------------------------
// Device helpers
// ---------------------------------------------------------------------------
// wave's A fragments (rows x0,x1; 32 k each strided by lg) with LN fold
__device__ __forceinline__ void ln_load_afrags(const float* __restrict__ x0,
                                               const float* __restrict__ x1,
                                               const float* __restrict__ st,
                                               int lg, bf16x8 aF[2][4]) {
#pragma unroll
  for (int kk = 0; kk < 4; ++kk) {
    const int k0 = (kk << 5) + (lg << 3);
    const fvec4 sA = *(const fvec4*)(st + k0);
    const fvec4 sB = *(const fvec4*)(st + k0 + 4);
    const fvec4 tA = *(const fvec4*)(st + 128 + k0);
    const fvec4 tB = *(const fvec4*)(st + 128 + k0 + 4);
    {
      const fvec4 v0 = *(const fvec4*)(x0 + k0);
      const fvec4 v1 = *(const fvec4*)(x0 + k0 + 4);
      u32x4 w;
      w[0] = cvtpk(v0[0] * sA[0] + tA[0], v0[1] * sA[1] + tA[1]);
      w[1] = cvtpk(v0[2] * sA[2] + tA[2], v0[3] * sA[3] + tA[3]);
      w[2] = cvtpk(v1[0] * sB[0] + tB[0], v1[1] * sB[1] + tB[1]);
      w[3] = cvtpk(v1[2] * sB[2] + tB[2], v1[3] * sB[3] + tB[3]);
      aF[0][kk] = __builtin_bit_cast(bf16x8, w);
    }
    {
      const fvec4 v0 = *(const fvec4*)(x1 + k0);
      const fvec4 v1 = *(const fvec4*)(x1 + k0 + 4);
      u32x4 w;
      w[0] = cvtpk(v0[0] * sA[0] + tA[0], v0[1] * sA[1] + tA[1]);
      w[1] = cvtpk(v0[2] * sA[2] + tA[2], v0[3] * sA[3] + tA[3]);
      w[2] = cvtpk(v1[0] * sB[0] + tB[0], v1[1] * sB[1] + tB[1]);
      w[3] = cvtpk(v1[2] * sB[2] + tB[2], v1[3] * sB[3] + tB[3]);
      aF[1][kk] = __builtin_bit_cast(bf16x8, w);
    }
  }
}

// acc[2][8] = Aregs(32 rows x 128k) @ B(128 cols x 128k) with B-frags from global
__device__ __forceinline__ void gemm_rA_gB(const bf16x8 aF[2][4], const u16* __restrict__ BT,
                                           int lr, int lg, f32x4 acc[2][8]) {
#pragma unroll
  for (int mt = 0; mt < 2; ++mt)
#pragma unroll
    for (int n = 0; n < 8; ++n) acc[mt][n] = (f32x4){0.f, 0.f, 0.f, 0.f};
#pragma unroll
  for (int kk = 0; kk < 4; ++kk) {
    const int ks = (kk << 5) + (lg << 3);
    bf16x8 bfr[8];
#pragma unroll
    for (int n = 0; n < 8; ++n)
      bfr[n] = *(const bf16x8*)&BT[(size_t)((n << 4) + lr) * 128 + ks];
#pragma unroll
    for (int mt = 0; mt < 2; ++mt)
#pragma unroll
      for (int n = 0; n < 8; ++n)
        acc[mt][n] = mfma16(aF[mt][kk], bfr[n], acc[mt][n]);
  }
}

// ---------------------------------------------------------------------------
// Wave-private fused attention: 1 wave = 1 head (its 32 tokens), NO barriers.
// Per-wave LDS: RK(8KB): K -> attL -> aout ; RQ(8KB): Q -> vT.
// ---------------------------------------------------------------------------
__global__ __launch_bounds__(128) void attn_fused_kernel(
    const u16* __restrict__ WqT,          // [384][128]
    const float* __restrict__ bqp,        // [384]
    const u16* __restrict__ WpT,          // [128][128]
    const float* __restrict__ bprj,       // [128]
    const float* __restrict__ st,         // [256] LN1 fold
    float* __restrict__ partials,         // rows 0..4095
    float* __restrict__ x)                // [131072][128] read + update
{
  __shared__ u16 lds[2][2][4096];
  const int tid = threadIdx.x;
  const int lane = tid & 63, wave = tid >> 6;
  const int lr = lane & 15, lg = lane >> 4;
  const int head = (blockIdx.x << 1) + wave;
  u16* RK = &lds[wave][0][0];
  u16* RQ = &lds[wave][1][0];

  // A fragments (LN1-folded): rows z = mt*16+lr of this head
  bf16x8 aF[2][4];
  ln_load_afrags(x + (((size_t)lr * 4096 + head) << 7),
                 x + (((size_t)(lr + 16) * 4096 + head) << 7), st, lg, aF);

  // --- K = A @ Wk -> RK [32 z][128 e] tix ---
  {
    f32x4 kacc[2][8];
    gemm_rA_gB(aF, WqT + 128 * 128, lr, lg, kacc);
#pragma unroll
    for (int n = 0; n < 8; ++n) {
      const int el = (n << 4) + lr;
      const float bb = bqp[128 + el];
#pragma unroll
      for (int mt = 0; mt < 2; ++mt)
#pragma unroll
        for (int rr = 0; rr < 4; ++rr)
          RK[tix((mt << 4) + (lg << 2) + rr, el)] = f2bf(kacc[mt][n][rr] + bb);
    }
  }
  // --- Q = A @ Wq -> RQ [32 z][128 e] tix ---
  {
    f32x4 qacc[2][8];
    gemm_rA_gB(aF, WqT, lr, lg, qacc);
#pragma unroll
    for (int n = 0; n < 8; ++n) {
      const int el = (n << 4) + lr;
      const float bb = bqp[el];
#pragma unroll
      for (int mt = 0; mt < 2; ++mt)
#pragma unroll
        for (int rr = 0; rr < 4; ++rr)
          RQ[tix((mt << 4) + (lg << 2) + rr, el)] = f2bf(qacc[mt][n][rr] + bb);
    }
  }

  // --- E^T = K @ Q^T (16 MFMA) ---
  f32x4 et[2][2];
#pragma unroll
  for (int mt = 0; mt < 2; ++mt)
#pragma unroll
    for (int nt = 0; nt < 2; ++nt) et[mt][nt] = (f32x4){0.f, 0.f, 0.f, 0.f};
#pragma unroll
  for (int kt = 0; kt < 4; ++kt) {
    const int ks = (kt << 5) + (lg << 3);
    bf16x8 ka[2], qb2[2];
#pragma unroll
    for (int t = 0; t < 2; ++t) {
      ka[t]  = *(const bf16x8*)&RK[tix((t << 4) + lr, ks)];
      qb2[t] = *(const bf16x8*)&RQ[tix((t << 4) + lr, ks)];
    }
#pragma unroll
    for (int mt = 0; mt < 2; ++mt)
#pragma unroll
      for (int nt = 0; nt < 2; ++nt)
        et[mt][nt] = mfma16(ka[mt], qb2[nt], et[mt][nt]);
  }

  // --- softmax over kz, /sqrt(128), *cm (verified) ---
  float p[2][2][4];
#pragma unroll
  for (int nt = 0; nt < 2; ++nt) {
    float mx = -1e30f;
#pragma unroll
    for (int mt = 0; mt < 2; ++mt)
#pragma unroll
      for (int r = 0; r < 4; ++r) mx = fmaxf(mx, et[mt][nt][r]);
    mx = fmaxf(mx, __shfl_xor(mx, 16));
    mx = fmaxf(mx, __shfl_xor(mx, 32));
    float s = 0.f;
#pragma unroll
    for (int mt = 0; mt < 2; ++mt)
#pragma unroll
      for (int r = 0; r < 4; ++r) {
        const float e = __expf(et[mt][nt][r] - mx);
        p[mt][nt][r] = e;
        s += e;
      }
    s += __shfl_xor(s, 16);
    s += __shfl_xor(s, 32);
    const float inv = 1.f / (s * 11.313708498984761f);   // *sqrt(128)
    const int qz = (nt << 4) + lr;
#pragma unroll
    for (int mt = 0; mt < 2; ++mt)
#pragma unroll
      for (int r = 0; r < 4; ++r) {
        const int kz = (mt << 4) + (lg << 2) + r;
        const float d = (float)(kz - qz);
        p[mt][nt][r] *= inv * __expf(d * d * (-1.f / 16.f));
      }
  }

  // P^T -> attL (RK start; K frags already consumed) [q][32 kz] chunk-swizzled
#pragma unroll
  for (int nt = 0; nt < 2; ++nt) {
    const int q = (nt << 4) + lr;
    const int qs = (q >> 1) & 3;
#pragma unroll
    for (int mt = 0; mt < 2; ++mt) {
      const int hc = (mt << 2) + lg;
      const int ch = (hc >> 1) ^ qs;
      const u32 lo = cvtpk(p[mt][nt][0], p[mt][nt][1]);
      const u32 hi = cvtpk(p[mt][nt][2], p[mt][nt][3]);
      *(u64*)&RK[(q << 5) + (ch << 3) + ((hc & 1) << 2)] = (u64)lo | ((u64)hi << 32);
    }
  }
  bf16x8 pa[2];
#pragma unroll
  for (int mt = 0; mt < 2; ++mt) {
    const int q = (mt << 4) + lr;
    pa[mt] = *(const bf16x8*)&RK[(q << 5) + ((lg ^ ((q >> 1) & 3)) << 3)];
  }

  // --- V = A @ Wv -> vT in RQ [128 e][32 kz] chunk-swizzled ---
  {
    f32x4 vacc[2][8];
    gemm_rA_gB(aF, WqT + 256 * 128, lr, lg, vacc);
#pragma unroll
    for (int n = 0; n < 8; ++n) {
      const int el = (n << 4) + lr;
      const float bb = bqp[256 + el];
#pragma unroll
      for (int mt = 0; mt < 2; ++mt)
#pragma unroll
        for (int rr = 0; rr < 4; ++rr) {
          const int kz = (mt << 4) + (lg << 2) + rr;
          RQ[(el << 5) + (((kz >> 3) ^ (el & 3)) << 3) + (kz & 7)] = f2bf(vacc[mt][n][rr] + bb);
        }
    }
  }

  // --- PV -> aout (RK, full region; attL dead after pa) [32 q][128 e] tix ---
#pragma unroll
  for (int n = 0; n < 8; ++n) {
    const int el = (n << 4) + lr;
    const bf16x8 vb = *(const bf16x8*)&RQ[(el << 5) + ((lg ^ (el & 3)) << 3)];
    const f32x4 z4 = (f32x4){0.f, 0.f, 0.f, 0.f};
    const f32x4 o0 = mfma16(pa[0], vb, z4);
    const f32x4 o1 = mfma16(pa[1], vb, z4);
#pragma unroll
    for (int rr = 0; rr < 4; ++rr) {
      const int q0 = (lg << 2) + rr;
      RK[tix(q0, el)] = f2bf(o0[rr]);
      RK[tix(q0 + 16, el)] = f2bf(o1[rr]);
    }
  }

  // --- proj: pacc = aout @ Wp (A from RK, B-frags global) ---
  f32x4 pacc[2][8];
#pragma unroll
  for (int mt = 0; mt < 2; ++mt)
#pragma unroll
    for (int n = 0; n < 8; ++n) pacc[mt][n] = (f32x4){0.f, 0.f, 0.f, 0.f};
#pragma unroll
  for (int kk = 0; kk < 4; ++kk) {
    const int ks = (kk << 5) + (lg << 3);
    bf16x8 af[2], bfr[8];
#pragma unroll
    for (int n = 0; n < 8; ++n)
      bfr[n] = *(const bf16x8*)&WpT[(size_t)((n << 4) + lr) * 128 + ks];
#pragma unroll
    for (int mt = 0; mt < 2; ++mt)
      af[mt] = *(const bf16x8*)&RK[tix((mt << 4) + lr, ks)];
#pragma unroll
    for (int mt = 0; mt < 2; ++mt)
#pragma unroll
      for (int n = 0; n < 8; ++n)
        pacc[mt][n] = mfma16(af[mt], bfr[n], pacc[mt][n]);
  }

  // --- epilogue: residual + LN2 stats (shfl-reduced, non-atomic) ---
  const int ws = (blockIdx.x << 1) + wave;
  float* pr = partials + (size_t)ws * 256;
#pragma unroll
  for (int n = 0; n < 8; ++n) {
    const int col = (n << 4) + lr;
    const float bb = bprj[col];
    float ssum = 0.f, qsum = 0.f;
#pragma unroll
    for (int mt = 0; mt < 2; ++mt) {
#pragma unroll
      for (int rr = 0; rr < 4; ++rr) {
        const int z = (mt << 4) + (lg << 2) + rr;
        const size_t gi = (((size_t)z * 4096 + head) << 7) + col;
        const float v = pacc[mt][n][rr] + bb + x[gi];
        x[gi] = v;
        ssum += v; qsum += v * v;
      }
    }
    ssum += __shfl_xor(ssum, 16); ssum += __shfl_xor(ssum, 32);
    qsum += __shfl_xor(qsum, 16); qsum += __shfl_xor(qsum, 32);
    if (lg == 0) { pr[col] = ssum; pr[128 + col] = qsum; }
  }
}

// ---------------------------------------------------------------------------
// Wave-private fused FFN: wave owns 32 consecutive rows, NO barriers.
// Weights as global fragments (L1/L2-hot). LDS: per-wave LH [32][64] only.
// ---------------------------------------------------------------------------
__global__ __launch_bounds__(256) void ffn_fused_kernel(
    const u16* __restrict__ W1T,    // [512][128]
    const float* __restrict__ b1,   // [512]
    const u16* __restrict__ W2T,    // [128][512]
    const float* __restrict__ b2,   // [128]
    const float* __restrict__ st,   // [256] LN2 fold
    float* __restrict__ partials,   // rows 0..4095
    float* __restrict__ x)
{
  __shared__ u16 LHall[4][2048];
  const int tid = threadIdx.x;
  const int lane = tid & 63, wave = tid >> 6;
  const int lr = lane & 15, lg = lane >> 4;
  const int r0 = (blockIdx.x << 7) + (wave << 5);
  u16* LH = &LHall[wave][0];

  bf16x8 aF[2][4];
  ln_load_afrags(x + ((size_t)(r0 + lr) << 7), x + ((size_t)(r0 + 16 + lr) << 7), st, lg, aF);

  f32x4 acc2[2][8];
#pragma unroll
  for (int mt = 0; mt < 2; ++mt)
#pragma unroll
    for (int n = 0; n < 8; ++n) acc2[mt][n] = (f32x4){0.f, 0.f, 0.f, 0.f};

#pragma unroll 1
  for (int c = 0; c < 8; ++c) {
    // gemm1: a1 = A @ W1 chunk (64 cols), B-frags from global
    f32x4 a1[2][4];
#pragma unroll
    for (int mt = 0; mt < 2; ++mt)
#pragma unroll
      for (int n = 0; n < 4; ++n) a1[mt][n] = (f32x4){0.f, 0.f, 0.f, 0.f};
#pragma unroll
    for (int kk = 0; kk < 4; ++kk) {
      const int ks = (kk << 5) + (lg << 3);
      bf16x8 bfr[4];
#pragma unroll
      for (int n = 0; n < 4; ++n)
        bfr[n] = *(const bf16x8*)&W1T[(size_t)((c << 6) + (n << 4) + lr) * 128 + ks];
#pragma unroll
      for (int mt = 0; mt < 2; ++mt)
#pragma unroll
        for (int n = 0; n < 4; ++n)
          a1[mt][n] = mfma16(aF[mt][kk], bfr[n], a1[mt][n]);
    }
    // h = hswish(a1 + b1) -> LH (own-wave; in-order LDS)
#pragma unroll
    for (int n = 0; n < 4; ++n) {
      const int hl = (n << 4) + lr;
      const float bb = b1[(c << 6) + hl];
#pragma unroll
      for (int mt = 0; mt < 2; ++mt)
#pragma unroll
        for (int rr = 0; rr < 4; ++rr) {
          const int rl = (mt << 4) + (lg << 2) + rr;
          const float h = a1[mt][n][rr] + bb;
          const float r6 = fminf(fmaxf(h + 3.f, 0.f), 6.f);
          LH[tix64(rl, hl)] = f2bf(h * r6 * (1.f / 6.f));
        }
    }
    // gemm2: acc2 += LH @ W2 chunk (B-frags from global)
#pragma unroll
    for (int kk = 0; kk < 2; ++kk) {
      const int ks = (kk << 5) + (lg << 3);
      bf16x8 af2[2], b2f[8];
#pragma unroll
      for (int n = 0; n < 8; ++n)
        b2f[n] = *(const bf16x8*)&W2T[(size_t)((n << 4) + lr) * 512 + (c << 6) + ks];
#pragma unroll
      for (int mt = 0; mt < 2; ++mt)
        af2[mt] = *(const bf16x8*)&LH[tix64((mt << 4) + lr, ks)];
#pragma unroll
      for (int mt = 0; mt < 2; ++mt)
#pragma unroll
        for (int n = 0; n < 8; ++n)
          acc2[mt][n] = mfma16(af2[mt], b2f[n], acc2[mt][n]);
    }
  }

  // epilogue: residual + next LN1 stats (shfl-reduced, non-atomic)
  const int ws = (blockIdx.x << 2) + wave;
  float* pr = partials + (size_t)ws * 256;
#pragma unroll
  for (int n = 0; n < 8; ++n) {
    const int col = (n << 4) + lr;
    const float bb = b2[col];
    float ssum = 0.f, qsum = 0.f;
#pragma unroll
    for (int mt = 0; mt < 2; ++mt) {
#pragma unroll
      for (int rr = 0; rr < 4; ++rr) {
        const int rl = (mt << 4) + (lg << 2) + rr;
        const size_t gi = ((size_t)(r0 + rl) << 7) + col;
        const float v = acc2[mt][n][rr] + bb + x[gi];
        x[gi] = v;
        ssum += v; qsum += v * v;
      }
    }
    ssum += __shfl_xor(ssum, 16); ssum += __shfl_xor(ssum, 32);
    qsum += __shfl_xor(qsum, 16); qsum += __shfl_xor(qsum, 32);
    if (lg == 0) { pr[col] = ssum; pr[128 + col] = qsum; }
  }
}

// ---------------------------------------------------------------------------
extern "C" void kernel_launch(void* const* d_in, const int* in_sizes, int n_in,
                              void* d_out, int out_size, void* d_ws, size_t ws_size,
                              hipStream_t stream)
{
  const float* img   = (const float*)d_in[0];
  const float* ln1g  = (const float*)d_in[1];
  const float* ln1b  = (const float*)d_in[2];
  const float* Wqkv  = (const float*)d_in[3];
  const float* bqkv  = (const float*)d_in[4];
  const float* Wproj = (const float*)d_in[5];
  const float* bproj = (const float*)d_in[6];
  const float* ln2g  = (const float*)d_in[7];
  const float* ln2b  = (const float*)d_in[8];
  const float* W1    = (const float*)d_in[9];
  const float* b1    = (const float*)d_in[10];
  const float* W2    = (const float*)d_in[11];
  const float* b2    = (const float*)d_in[12];

  char* ws = (char*)d_ws;
  float* x = (float*)ws;                              // 64 MB
  char* wsw = ws + ((size_t)64 << 20);
  u16* WqT = (u16*)wsw;                               // 3*49152
  u16* WpT = WqT + 3 * 49152;                         // 3*16384
  u16* W1T = WpT + 3 * 16384;                         // 3*65536
  u16* W2T = W1T + 3 * 65536;                         // 3*65536
  float* bqp = (float*)(W2T + 3 * 65536);             // 3*384
  float* S   = bqp + 3 * 384;                         // 7*256 fold params
  float* bred = S + 7 * 256;                          // 64*256 stage-1 sums
  float* partials = bred + 64 * 256;                  // 6144*256 (attn/ffn rows 0..4095, tin 4096..6143)

  prep_kernel<<<2309, 256, 0, stream>>>(Wqkv, bqkv, Wproj, W1, W2, WqT, WpT, W1T, W2T, bqp);
  tin_kernel<<<2048, 256, 0, stream>>>(img, x, partials, 4096);
  reduce1_kernel<<<64, 256, 0, stream>>>(partials, 4096, 2048, bred);
  finalize_kernel<<<1, 128, 0, stream>>>(bred, ln1g, ln1b, S);

  for (int d = 0; d < 3; ++d) {
    float* st1 = S + (2 * d) * 256;
    float* st2 = S + (2 * d + 1) * 256;
    attn_fused_kernel<<<2048, 128, 0, stream>>>(
        WqT + d * 49152, bqp + d * 384, WpT + d * 16384, bproj + d * 128,
        st1, partials, x);
    reduce1_kernel<<<64, 256, 0, stream>>>(partials, 0, 4096, bred);
    finalize_kernel<<<1, 128, 0, stream>>>(bred, ln2g + d * 128, ln2b + d * 128, st2);
    ffn_fused_kernel<<<1024, 256, 0, stream>>>(
        W1T + d * 65536, b1 + d * 512, W2T + d * 65536, b2 + d * 128,
        st2, partials, x);
    if (d < 2) {
      reduce1_kernel<<<64, 256, 0, stream>>>(partials, 0, 4096, bred);
      finalize_kernel<<<1, 128, 0, stream>>>(bred, ln1g + (d + 1) * 128, ln1b + (d + 1) * 128,
                                             S + (2 * d + 2) * 256);
    }
  }

  tout_kernel<<<2048, 256, 0, stream>>>(x, (float*)d_out);
}

// Round 7
// 796.146 us; speedup vs baseline: 1.3191x; 1.3191x over previous
//
#include <hip/hip_runtime.h>
#include <hip/hip_bf16.h>

typedef __attribute__((ext_vector_type(8))) short bf16x8;
typedef __attribute__((ext_vector_type(4))) float f32x4;
typedef __attribute__((ext_vector_type(4))) float fvec4;
typedef __attribute__((ext_vector_type(4))) unsigned int u32x4;
typedef unsigned short u16;
typedef unsigned int u32;
typedef unsigned long long u64;

#define N_TOK 131072

__device__ __forceinline__ u32 cvtpk(float lo, float hi) {
  u32 r; asm("v_cvt_pk_bf16_f32 %0, %1, %2" : "=v"(r) : "v"(lo), "v"(hi)); return r;
}
__device__ __forceinline__ u16 f2bf(float f) { return (u16)cvtpk(f, f); }

__device__ __forceinline__ f32x4 mfma16(bf16x8 a, bf16x8 b, f32x4 c) {
  return __builtin_amdgcn_mfma_f32_16x16x32_bf16(a, b, c, 0, 0, 0);
}

// swizzled index into [rows][128 shorts] LDS tile: 16B-chunk XOR row&15
__device__ __forceinline__ int tix(int row, int s) {
  return (row << 7) + ((((s >> 3) ^ (row & 15))) << 3) + (s & 7);
}
// swizzled index into [rows][64 shorts] LDS tile
__device__ __forceinline__ int tix64(int row, int s) {
  return (row << 6) + ((((s >> 3) ^ (row & 7))) << 3) + (s & 7);
}

// ---------------------------------------------------------------------------
// Weight prep: bf16, de-interleaved, FRAGMENT-ORDERED so every kernel B-load
// is F + group*1KB + lane*16B (fully coalesced).
//  WqF [3 which][kk4][n8][lane][8]   (e = n*16+lr, k = kk*32+lg*8+j)
//  WpF [kk4][n8][lane][8]
//  W1F [c8][kk4][n4][lane][8]        (col = c*64+n*16+lr)
//  W2F [c8][kk2][n8][lane][8]        (k = c*64+kk*32+lg*8+j)
// ---------------------------------------------------------------------------
__global__ __launch_bounds__(256) void prep_kernel(
    const float* __restrict__ Wqkv, const float* __restrict__ bqkv,
    const float* __restrict__ Wproj, const float* __restrict__ W1,
    const float* __restrict__ W2,
    u16* __restrict__ WqF, u16* __restrict__ WpF,
    u16* __restrict__ W1F, u16* __restrict__ W2F,
    float* __restrict__ bqp)
{
  const int gid = blockIdx.x * 256 + threadIdx.x;
  if (gid < 73728) {
    const int d = gid / 24576, g = gid % 24576;
    if (g < 6144) {                       // qkv
      const int which = g >> 11, r = g & 2047;
      const int kk = r >> 9, n = (r >> 6) & 7, lane = r & 63;
      const int lr = lane & 15, lg = lane >> 4;
      const int e = (n << 4) + lr;
      u16* dst = WqF + d * 49152 + which * 16384 + (((kk << 3) + n) << 9) + (lane << 3);
      const float* src = Wqkv + (size_t)d * 49152;
#pragma unroll
      for (int j = 0; j < 8; ++j)
        dst[j] = f2bf(src[(size_t)((kk << 5) + (lg << 3) + j) * 384 + e * 3 + which]);
    } else if (g < 8192) {                // proj
      const int r = g - 6144;
      const int kk = r >> 9, n = (r >> 6) & 7, lane = r & 63;
      const int lr = lane & 15, lg = lane >> 4;
      const int col = (n << 4) + lr;
      u16* dst = WpF + d * 16384 + (((kk << 3) + n) << 9) + (lane << 3);
      const float* src = Wproj + (size_t)d * 16384;
#pragma unroll
      for (int j = 0; j < 8; ++j)
        dst[j] = f2bf(src[(size_t)((kk << 5) + (lg << 3) + j) * 128 + col]);
    } else if (g < 16384) {               // W1
      const int r = g - 8192;
      const int c = r >> 10, kk = (r >> 8) & 3, n = (r >> 6) & 3, lane = r & 63;
      const int lr = lane & 15, lg = lane >> 4;
      const int col = (c << 6) + (n << 4) + lr;
      u16* dst = W1F + d * 65536 + ((((c << 2) + kk) << 2) + n) * 512 + (lane << 3);
      const float* src = W1 + (size_t)d * 65536;
#pragma unroll
      for (int j = 0; j < 8; ++j)
        dst[j] = f2bf(src[(size_t)((kk << 5) + (lg << 3) + j) * 512 + col]);
    } else {                              // W2
      const int r = g - 16384;
      const int c = r >> 10, kk = (r >> 9) & 1, n = (r >> 6) & 7, lane = r & 63;
      const int lr = lane & 15, lg = lane >> 4;
      const int col = (n << 4) + lr;
      u16* dst = W2F + d * 65536 + ((((c << 1) + kk) << 3) + n) * 512 + (lane << 3);
      const float* src = W2 + (size_t)d * 65536;
#pragma unroll
      for (int j = 0; j < 8; ++j)
        dst[j] = f2bf(src[(size_t)((c << 6) + (kk << 5) + (lg << 3) + j) * 128 + col]);
    }
  } else if (gid < 73728 + 1152) {
    const int i2 = gid - 73728; const int d = i2 / 384, c = i2 % 384;
    bqp[i2] = bqkv[d * 384 + (c & 127) * 3 + (c >> 7)];
  }
}

// ---------------------------------------------------------------------------
// img [128][131072] f32 -> x2 HEAD-MAJOR [4096 h][32 z][128] f32 + LN1 stats.
// Block handles 64 consecutive tokens (one z, 64 heads).
// ---------------------------------------------------------------------------
__global__ __launch_bounds__(256) void tin_kernel(const float* __restrict__ img,
                                                  float* __restrict__ x2,
                                                  float* __restrict__ partials,
                                                  int prow0)
{
  __shared__ float t[128 * 65];
  __shared__ float ssum[256], sqq[256];
  const int t0 = blockIdx.x * 64;
  const int z = t0 >> 12, h0 = t0 & 4095;
  const int tid = threadIdx.x;
  {
    const int j = tid & 63, cq = tid >> 6;
    for (int c = cq; c < 128; c += 4) t[c * 65 + j] = img[(size_t)c * N_TOK + t0 + j];
  }
  __syncthreads();
  {
    const int c = tid & 127, jh = tid >> 7;
    float s = 0.f, q = 0.f;
    for (int jj = jh; jj < 64; jj += 2) {
      const float v = t[c * 65 + jj];
      x2[(size_t)((h0 + jj) * 32 + z) * 128 + c] = v;
      s += v; q += v * v;
    }
    ssum[tid] = s; sqq[tid] = q;
  }
  __syncthreads();
  if (tid < 128) {
    float* pr = partials + (size_t)(prow0 + blockIdx.x) * 256;
    pr[tid] = ssum[tid] + ssum[tid + 128];
    pr[128 + tid] = sqq[tid] + sqq[tid + 128];
  }
}

// x2 head-major -> out [128][131072] with relu
__global__ __launch_bounds__(256) void tout_kernel(const float* __restrict__ x2,
                                                   float* __restrict__ out)
{
  __shared__ float t[128 * 65];
  const int t0 = blockIdx.x * 64;
  const int z = t0 >> 12, h0 = t0 & 4095;
  const int tid = threadIdx.x;
  {
    const int c = tid & 127, jh = tid >> 7;
    for (int jj = jh; jj < 64; jj += 2)
      t[c * 65 + jj] = x2[(size_t)((h0 + jj) * 32 + z) * 128 + c];
  }
  __syncthreads();
  {
    const int j = tid & 63, cq = tid >> 6;
    for (int c = cq; c < 128; c += 4)
      out[(size_t)c * N_TOK + t0 + j] = fmaxf(t[c * 65 + j], 0.f);
  }
}

// stage-1 reduce
__global__ __launch_bounds__(256) void reduce1_kernel(const float* __restrict__ p,
                                                      int rows0, int nrows,
                                                      float* __restrict__ bred)
{
  const int chunk = nrows >> 6;
  const float* base = p + (size_t)(rows0 + blockIdx.x * chunk) * 256;
  float s = 0.f;
  for (int r = 0; r < chunk; ++r) s += base[r * 256 + threadIdx.x];
  bred[blockIdx.x * 256 + threadIdx.x] = s;
}

__global__ void finalize_kernel(const float* __restrict__ bred, const float* __restrict__ g,
                                const float* __restrict__ b, float* __restrict__ st)
{
  const int c = threadIdx.x;   // 128
  float s = 0.f, q = 0.f;
  for (int r = 0; r < 64; ++r) { s += bred[r * 256 + c]; q += bred[r * 256 + 128 + c]; }
  const float inv = 1.f / 131072.f;
  const float mu = s * inv;
  const float var = q * inv - mu * mu;
  const float sc = g[c] * rsqrtf(var + 1e-5f);
  st[c] = sc;
  st[128 + c] = b[c] - mu * sc;
}

// ---------------------------------------------------------------------------
// Device helpers
// ---------------------------------------------------------------------------
__device__ __forceinline__ void ln_load_afrags(const float* __restrict__ x0,
                                               const float* __restrict__ x1,
                                               const float* __restrict__ st,
                                               int lg, bf16x8 aF[2][4]) {
#pragma unroll
  for (int kk = 0; kk < 4; ++kk) {
    const int k0 = (kk << 5) + (lg << 3);
    const fvec4 sA = *(const fvec4*)(st + k0);
    const fvec4 sB = *(const fvec4*)(st + k0 + 4);
    const fvec4 tA = *(const fvec4*)(st + 128 + k0);
    const fvec4 tB = *(const fvec4*)(st + 128 + k0 + 4);
    {
      const fvec4 v0 = *(const fvec4*)(x0 + k0);
      const fvec4 v1 = *(const fvec4*)(x0 + k0 + 4);
      u32x4 w;
      w[0] = cvtpk(v0[0] * sA[0] + tA[0], v0[1] * sA[1] + tA[1]);
      w[1] = cvtpk(v0[2] * sA[2] + tA[2], v0[3] * sA[3] + tA[3]);
      w[2] = cvtpk(v1[0] * sB[0] + tB[0], v1[1] * sB[1] + tB[1]);
      w[3] = cvtpk(v1[2] * sB[2] + tB[2], v1[3] * sB[3] + tB[3]);
      aF[0][kk] = __builtin_bit_cast(bf16x8, w);
    }
    {
      const fvec4 v0 = *(const fvec4*)(x1 + k0);
      const fvec4 v1 = *(const fvec4*)(x1 + k0 + 4);
      u32x4 w;
      w[0] = cvtpk(v0[0] * sA[0] + tA[0], v0[1] * sA[1] + tA[1]);
      w[1] = cvtpk(v0[2] * sA[2] + tA[2], v0[3] * sA[3] + tA[3]);
      w[2] = cvtpk(v1[0] * sB[0] + tB[0], v1[1] * sB[1] + tB[1]);
      w[3] = cvtpk(v1[2] * sB[2] + tB[2], v1[3] * sB[3] + tB[3]);
      aF[1][kk] = __builtin_bit_cast(bf16x8, w);
    }
  }
}

// acc[2][8] = Aregs @ B, B from FRAGMENT-ORDERED buffer (coalesced 1KB loads)
__device__ __forceinline__ void gemm_rA_fB8(const bf16x8 aF[2][4], const u16* __restrict__ F,
                                            int lane, f32x4 acc[2][8]) {
#pragma unroll
  for (int mt = 0; mt < 2; ++mt)
#pragma unroll
    for (int n = 0; n < 8; ++n) acc[mt][n] = (f32x4){0.f, 0.f, 0.f, 0.f};
#pragma unroll
  for (int kk = 0; kk < 4; ++kk) {
    bf16x8 bfr[8];
#pragma unroll
    for (int n = 0; n < 8; ++n)
      bfr[n] = *(const bf16x8*)&F[((((kk << 3) + n) << 9)) + (lane << 3)];
#pragma unroll
    for (int mt = 0; mt < 2; ++mt)
#pragma unroll
      for (int n = 0; n < 8; ++n)
        acc[mt][n] = mfma16(aF[mt][kk], bfr[n], acc[mt][n]);
  }
}

// epilogue: acc -> LDS transpose (stride 65) -> coalesced residual RMW on x
// + per-col stats -> partials row. Wave-private (no barriers).
__device__ __forceinline__ void epi(const f32x4 acc[2][8], float* __restrict__ fb,
                                    float* __restrict__ xr, const float* __restrict__ bias,
                                    float* __restrict__ pr, int lr, int lg) {
#pragma unroll
  for (int ch = 0; ch < 2; ++ch) {
#pragma unroll
    for (int n = 0; n < 4; ++n) {
      const int cl = (n << 4) + lr;
      const float bb = bias[(ch << 6) + cl];
#pragma unroll
      for (int mt = 0; mt < 2; ++mt)
#pragma unroll
        for (int rr = 0; rr < 4; ++rr)
          fb[((mt << 4) + (lg << 2) + rr) * 65 + cl] = acc[mt][(ch << 2) + n][rr] + bb;
    }
    float s0 = 0, s1 = 0, s2 = 0, s3 = 0, q0 = 0, q1 = 0, q2 = 0, q3 = 0;
#pragma unroll
    for (int i = 0; i < 8; ++i) {
      const int row = (i << 2) + lg;
      const int cb = lr << 2;
      const float v0 = fb[row * 65 + cb + 0];
      const float v1 = fb[row * 65 + cb + 1];
      const float v2 = fb[row * 65 + cb + 2];
      const float v3 = fb[row * 65 + cb + 3];
      float* gx = xr + row * 128 + (ch << 6) + cb;
      fvec4 g = *(const fvec4*)gx;
      g[0] += v0; g[1] += v1; g[2] += v2; g[3] += v3;
      *(fvec4*)gx = g;
      s0 += g[0]; q0 += g[0] * g[0];
      s1 += g[1]; q1 += g[1] * g[1];
      s2 += g[2]; q2 += g[2] * g[2];
      s3 += g[3]; q3 += g[3] * g[3];
    }
    s0 += __shfl_xor(s0, 16); s0 += __shfl_xor(s0, 32);
    s1 += __shfl_xor(s1, 16); s1 += __shfl_xor(s1, 32);
    s2 += __shfl_xor(s2, 16); s2 += __shfl_xor(s2, 32);
    s3 += __shfl_xor(s3, 16); s3 += __shfl_xor(s3, 32);
    q0 += __shfl_xor(q0, 16); q0 += __shfl_xor(q0, 32);
    q1 += __shfl_xor(q1, 16); q1 += __shfl_xor(q1, 32);
    q2 += __shfl_xor(q2, 16); q2 += __shfl_xor(q2, 32);
    q3 += __shfl_xor(q3, 16); q3 += __shfl_xor(q3, 32);
    if (lg == 0) {
      *(fvec4*)&pr[(ch << 6) + (lr << 2)] = (fvec4){s0, s1, s2, s3};
      *(fvec4*)&pr[128 + (ch << 6) + (lr << 2)] = (fvec4){q0, q1, q2, q3};
    }
  }
}

// ---------------------------------------------------------------------------
// Wave-private fused attention: 1 wave = 1 head, x2 head-major (contiguous).
// ---------------------------------------------------------------------------
__global__ __launch_bounds__(128) void attn_fused_kernel(
    const u16* __restrict__ WF,           // frag-ordered [3][16384]
    const float* __restrict__ bqp,        // [384]
    const u16* __restrict__ WpF,          // frag-ordered [16384]
    const float* __restrict__ bprj,       // [128]
    const float* __restrict__ st,         // [256] LN1 fold
    float* __restrict__ partials,
    float* __restrict__ x2)               // head-major [4096*32][128]
{
  __shared__ u16 lds[2][2][4096];
  const int tid = threadIdx.x;
  const int lane = tid & 63, wave = tid >> 6;
  const int lr = lane & 15, lg = lane >> 4;
  const int head = (blockIdx.x << 1) + wave;
  u16* RK = &lds[wave][0][0];
  u16* RQ = &lds[wave][1][0];
  float* xh = x2 + ((size_t)head << 12);   // head*32*128

  bf16x8 aF[2][4];
  ln_load_afrags(xh + (lr << 7), xh + ((lr + 16) << 7), st, lg, aF);

  // K -> RK, Q -> RQ
  {
    f32x4 kacc[2][8];
    gemm_rA_fB8(aF, WF + 16384, lane, kacc);
#pragma unroll
    for (int n = 0; n < 8; ++n) {
      const int el = (n << 4) + lr;
      const float bb = bqp[128 + el];
#pragma unroll
      for (int mt = 0; mt < 2; ++mt)
#pragma unroll
        for (int rr = 0; rr < 4; ++rr)
          RK[tix((mt << 4) + (lg << 2) + rr, el)] = f2bf(kacc[mt][n][rr] + bb);
    }
  }
  {
    f32x4 qacc[2][8];
    gemm_rA_fB8(aF, WF, lane, qacc);
#pragma unroll
    for (int n = 0; n < 8; ++n) {
      const int el = (n << 4) + lr;
      const float bb = bqp[el];
#pragma unroll
      for (int mt = 0; mt < 2; ++mt)
#pragma unroll
        for (int rr = 0; rr < 4; ++rr)
          RQ[tix((mt << 4) + (lg << 2) + rr, el)] = f2bf(qacc[mt][n][rr] + bb);
    }
  }

  // E^T = K @ Q^T
  f32x4 et[2][2];
#pragma unroll
  for (int mt = 0; mt < 2; ++mt)
#pragma unroll
    for (int nt = 0; nt < 2; ++nt) et[mt][nt] = (f32x4){0.f, 0.f, 0.f, 0.f};
#pragma unroll
  for (int kt = 0; kt < 4; ++kt) {
    const int ks = (kt << 5) + (lg << 3);
    bf16x8 ka[2], qb2[2];
#pragma unroll
    for (int t = 0; t < 2; ++t) {
      ka[t]  = *(const bf16x8*)&RK[tix((t << 4) + lr, ks)];
      qb2[t] = *(const bf16x8*)&RQ[tix((t << 4) + lr, ks)];
    }
#pragma unroll
    for (int mt = 0; mt < 2; ++mt)
#pragma unroll
      for (int nt = 0; nt < 2; ++nt)
        et[mt][nt] = mfma16(ka[mt], qb2[nt], et[mt][nt]);
  }

  // softmax over kz, /sqrt(128), *cm (verified math)
  float p[2][2][4];
#pragma unroll
  for (int nt = 0; nt < 2; ++nt) {
    float mx = -1e30f;
#pragma unroll
    for (int mt = 0; mt < 2; ++mt)
#pragma unroll
      for (int r = 0; r < 4; ++r) mx = fmaxf(mx, et[mt][nt][r]);
    mx = fmaxf(mx, __shfl_xor(mx, 16));
    mx = fmaxf(mx, __shfl_xor(mx, 32));
    float s = 0.f;
#pragma unroll
    for (int mt = 0; mt < 2; ++mt)
#pragma unroll
      for (int r = 0; r < 4; ++r) {
        const float e = __expf(et[mt][nt][r] - mx);
        p[mt][nt][r] = e;
        s += e;
      }
    s += __shfl_xor(s, 16);
    s += __shfl_xor(s, 32);
    const float inv = 1.f / (s * 11.313708498984761f);
    const int qz = (nt << 4) + lr;
#pragma unroll
    for (int mt = 0; mt < 2; ++mt)
#pragma unroll
      for (int r = 0; r < 4; ++r) {
        const int kz = (mt << 4) + (lg << 2) + r;
        const float d = (float)(kz - qz);
        p[mt][nt][r] *= inv * __expf(d * d * (-1.f / 16.f));
      }
  }

  // P^T -> attL (RK head region; K frags consumed)
#pragma unroll
  for (int nt = 0; nt < 2; ++nt) {
    const int q = (nt << 4) + lr;
    const int qs = (q >> 1) & 3;
#pragma unroll
    for (int mt = 0; mt < 2; ++mt) {
      const int hc = (mt << 2) + lg;
      const int ch = (hc >> 1) ^ qs;
      const u32 lo = cvtpk(p[mt][nt][0], p[mt][nt][1]);
      const u32 hi = cvtpk(p[mt][nt][2], p[mt][nt][3]);
      *(u64*)&RK[(q << 5) + (ch << 3) + ((hc & 1) << 2)] = (u64)lo | ((u64)hi << 32);
    }
  }
  bf16x8 pa[2];
#pragma unroll
  for (int mt = 0; mt < 2; ++mt) {
    const int q = (mt << 4) + lr;
    pa[mt] = *(const bf16x8*)&RK[(q << 5) + ((lg ^ ((q >> 1) & 3)) << 3)];
  }

  // V -> vT in RQ
  {
    f32x4 vacc[2][8];
    gemm_rA_fB8(aF, WF + 32768, lane, vacc);
#pragma unroll
    for (int n = 0; n < 8; ++n) {
      const int el = (n << 4) + lr;
      const float bb = bqp[256 + el];
#pragma unroll
      for (int mt = 0; mt < 2; ++mt)
#pragma unroll
        for (int rr = 0; rr < 4; ++rr) {
          const int kz = (mt << 4) + (lg << 2) + rr;
          RQ[(el << 5) + (((kz >> 3) ^ (el & 3)) << 3) + (kz & 7)] = f2bf(vacc[mt][n][rr] + bb);
        }
    }
  }

  // PV -> aout (RK)
#pragma unroll
  for (int n = 0; n < 8; ++n) {
    const int el = (n << 4) + lr;
    const bf16x8 vb = *(const bf16x8*)&RQ[(el << 5) + ((lg ^ (el & 3)) << 3)];
    const f32x4 z4 = (f32x4){0.f, 0.f, 0.f, 0.f};
    const f32x4 o0 = mfma16(pa[0], vb, z4);
    const f32x4 o1 = mfma16(pa[1], vb, z4);
#pragma unroll
    for (int rr = 0; rr < 4; ++rr) {
      const int q0 = (lg << 2) + rr;
      RK[tix(q0, el)] = f2bf(o0[rr]);
      RK[tix(q0 + 16, el)] = f2bf(o1[rr]);
    }
  }

  // proj: aout @ Wp (frag-ordered B)
  f32x4 pacc[2][8];
#pragma unroll
  for (int mt = 0; mt < 2; ++mt)
#pragma unroll
    for (int n = 0; n < 8; ++n) pacc[mt][n] = (f32x4){0.f, 0.f, 0.f, 0.f};
#pragma unroll
  for (int kk = 0; kk < 4; ++kk) {
    const int ks = (kk << 5) + (lg << 3);
    bf16x8 af[2], bfr[8];
#pragma unroll
    for (int n = 0; n < 8; ++n)
      bfr[n] = *(const bf16x8*)&WpF[(((kk << 3) + n) << 9) + (lane << 3)];
#pragma unroll
    for (int mt = 0; mt < 2; ++mt)
      af[mt] = *(const bf16x8*)&RK[tix((mt << 4) + lr, ks)];
#pragma unroll
    for (int mt = 0; mt < 2; ++mt)
#pragma unroll
      for (int n = 0; n < 8; ++n)
        pacc[mt][n] = mfma16(af[mt], bfr[n], pacc[mt][n]);
  }

  // epilogue: LDS-transpose (reuse wave's 16KB region) + coalesced RMW
  epi(pacc, (float*)&lds[wave][0][0], xh, bprj,
      partials + (size_t)((blockIdx.x << 1) + wave) * 256, lr, lg);
}

// ---------------------------------------------------------------------------
// Wave-private fused FFN: wave owns 32 rows; frag-ordered weights; no barriers.
// ---------------------------------------------------------------------------
__global__ __launch_bounds__(256) void ffn_fused_kernel(
    const u16* __restrict__ W1F,    // [8][4][4][64][8]
    const float* __restrict__ b1,   // [512]
    const u16* __restrict__ W2F,    // [8][2][8][64][8]
    const float* __restrict__ b2,   // [128]
    const float* __restrict__ st,   // [256] LN2 fold
    float* __restrict__ partials,
    float* __restrict__ x2)
{
  __shared__ u16 LHall[4][2048];
  __shared__ float fball[4][2112];
  const int tid = threadIdx.x;
  const int lane = tid & 63, wave = tid >> 6;
  const int lr = lane & 15, lg = lane >> 4;
  const int r0 = (blockIdx.x << 7) + (wave << 5);
  u16* LH = &LHall[wave][0];
  float* xr = x2 + ((size_t)r0 << 7);

  bf16x8 aF[2][4];
  ln_load_afrags(xr + (lr << 7), xr + ((lr + 16) << 7), st, lg, aF);

  f32x4 acc2[2][8];
#pragma unroll
  for (int mt = 0; mt < 2; ++mt)
#pragma unroll
    for (int n = 0; n < 8; ++n) acc2[mt][n] = (f32x4){0.f, 0.f, 0.f, 0.f};

#pragma unroll 1
  for (int c = 0; c < 8; ++c) {
    // gemm1: a1 = A @ W1c (coalesced frag loads)
    const u16* F1c = W1F + (c << 13);
    f32x4 a1[2][4];
#pragma unroll
    for (int mt = 0; mt < 2; ++mt)
#pragma unroll
      for (int n = 0; n < 4; ++n) a1[mt][n] = (f32x4){0.f, 0.f, 0.f, 0.f};
#pragma unroll
    for (int kk = 0; kk < 4; ++kk) {
      bf16x8 bfr[4];
#pragma unroll
      for (int n = 0; n < 4; ++n)
        bfr[n] = *(const bf16x8*)&F1c[(((kk << 2) + n) << 9) + (lane << 3)];
#pragma unroll
      for (int mt = 0; mt < 2; ++mt)
#pragma unroll
        for (int n = 0; n < 4; ++n)
          a1[mt][n] = mfma16(aF[mt][kk], bfr[n], a1[mt][n]);
    }
    // h = hswish -> LH (own-wave)
#pragma unroll
    for (int n = 0; n < 4; ++n) {
      const int hl = (n << 4) + lr;
      const float bb = b1[(c << 6) + hl];
#pragma unroll
      for (int mt = 0; mt < 2; ++mt)
#pragma unroll
        for (int rr = 0; rr < 4; ++rr) {
          const int rl = (mt << 4) + (lg << 2) + rr;
          const float h = a1[mt][n][rr] + bb;
          const float r6 = fminf(fmaxf(h + 3.f, 0.f), 6.f);
          LH[tix64(rl, hl)] = f2bf(h * r6 * (1.f / 6.f));
        }
    }
    // gemm2: acc2 += LH @ W2c (coalesced frag loads)
    const u16* F2c = W2F + (c << 13);
#pragma unroll
    for (int kk = 0; kk < 2; ++kk) {
      const int ks = (kk << 5) + (lg << 3);
      bf16x8 af2[2], b2f[8];
#pragma unroll
      for (int n = 0; n < 8; ++n)
        b2f[n] = *(const bf16x8*)&F2c[(((kk << 3) + n) << 9) + (lane << 3)];
#pragma unroll
      for (int mt = 0; mt < 2; ++mt)
        af2[mt] = *(const bf16x8*)&LH[tix64((mt << 4) + lr, ks)];
#pragma unroll
      for (int mt = 0; mt < 2; ++mt)
#pragma unroll
        for (int n = 0; n < 8; ++n)
          acc2[mt][n] = mfma16(af2[mt], b2f[n], acc2[mt][n]);
    }
  }

  epi(acc2, &fball[wave][0], xr, b2,
      partials + (size_t)((blockIdx.x << 2) + wave) * 256, lr, lg);
}

// ---------------------------------------------------------------------------
extern "C" void kernel_launch(void* const* d_in, const int* in_sizes, int n_in,
                              void* d_out, int out_size, void* d_ws, size_t ws_size,
                              hipStream_t stream)
{
  const float* img   = (const float*)d_in[0];
  const float* ln1g  = (const float*)d_in[1];
  const float* ln1b  = (const float*)d_in[2];
  const float* Wqkv  = (const float*)d_in[3];
  const float* bqkv  = (const float*)d_in[4];
  const float* Wproj = (const float*)d_in[5];
  const float* bproj = (const float*)d_in[6];
  const float* ln2g  = (const float*)d_in[7];
  const float* ln2b  = (const float*)d_in[8];
  const float* W1    = (const float*)d_in[9];
  const float* b1    = (const float*)d_in[10];
  const float* W2    = (const float*)d_in[11];
  const float* b2    = (const float*)d_in[12];

  char* ws = (char*)d_ws;
  float* x2 = (float*)ws;                             // 64 MB head-major
  char* wsw = ws + ((size_t)64 << 20);
  u16* WqF = (u16*)wsw;                               // 3*49152
  u16* WpF = WqF + 3 * 49152;                         // 3*16384
  u16* W1F = WpF + 3 * 16384;                         // 3*65536
  u16* W2F = W1F + 3 * 65536;                         // 3*65536
  float* bqp = (float*)(W2F + 3 * 65536);             // 3*384
  float* S   = bqp + 3 * 384;                         // 7*256 fold params
  float* bred = S + 7 * 256;                          // 64*256
  float* partials = bred + 64 * 256;                  // 6144*256

  prep_kernel<<<293, 256, 0, stream>>>(Wqkv, bqkv, Wproj, W1, W2, WqF, WpF, W1F, W2F, bqp);
  tin_kernel<<<2048, 256, 0, stream>>>(img, x2, partials, 4096);
  reduce1_kernel<<<64, 256, 0, stream>>>(partials, 4096, 2048, bred);
  finalize_kernel<<<1, 128, 0, stream>>>(bred, ln1g, ln1b, S);

  for (int d = 0; d < 3; ++d) {
    float* st1 = S + (2 * d) * 256;
    float* st2 = S + (2 * d + 1) * 256;
    attn_fused_kernel<<<2048, 128, 0, stream>>>(
        WqF + d * 49152, bqp + d * 384, WpF + d * 16384, bproj + d * 128,
        st1, partials, x2);
    reduce1_kernel<<<64, 256, 0, stream>>>(partials, 0, 4096, bred);
    finalize_kernel<<<1, 128, 0, stream>>>(bred, ln2g + d * 128, ln2b + d * 128, st2);
    ffn_fused_kernel<<<1024, 256, 0, stream>>>(
        W1F + d * 65536, b1 + d * 512, W2F + d * 65536, b2 + d * 128,
        st2, partials, x2);
    if (d < 2) {
      reduce1_kernel<<<64, 256, 0, stream>>>(partials, 0, 4096, bred);
      finalize_kernel<<<1, 128, 0, stream>>>(bred, ln1g + (d + 1) * 128, ln1b + (d + 1) * 128,
                                             S + (2 * d + 2) * 256);
    }
  }

  tout_kernel<<<2048, 256, 0, stream>>>(x2, (float*)d_out);
}

// Round 8
// 791.851 us; speedup vs baseline: 1.3263x; 1.0054x over previous
//
#include <hip/hip_runtime.h>
#include <hip/hip_bf16.h>

typedef __attribute__((ext_vector_type(8))) short bf16x8;
typedef __attribute__((ext_vector_type(4))) float f32x4;
typedef __attribute__((ext_vector_type(4))) float fvec4;
typedef __attribute__((ext_vector_type(4))) unsigned int u32x4;
typedef unsigned short u16;
typedef unsigned int u32;
typedef unsigned long long u64;

#define N_TOK 131072

__device__ __forceinline__ u32 cvtpk(float lo, float hi) {
  u32 r; asm("v_cvt_pk_bf16_f32 %0, %1, %2" : "=v"(r) : "v"(lo), "v"(hi)); return r;
}
__device__ __forceinline__ u16 f2bf(float f) { return (u16)cvtpk(f, f); }

__device__ __forceinline__ f32x4 mfma16(bf16x8 a, bf16x8 b, f32x4 c) {
  return __builtin_amdgcn_mfma_f32_16x16x32_bf16(a, b, c, 0, 0, 0);
}

// swizzled index into [rows][128 shorts] LDS tile: 16B-chunk XOR row&15
__device__ __forceinline__ int tix(int row, int s) {
  return (row << 7) + ((((s >> 3) ^ (row & 15))) << 3) + (s & 7);
}
// swizzled index into [rows][32 shorts] LDS tile: 4 chunks XOR (row>>1)&3
__device__ __forceinline__ int lh32(int row, int s) {
  return (row << 5) + ((((s >> 3) ^ ((row >> 1) & 3))) << 3) + (s & 7);
}

// ---------------------------------------------------------------------------
// Weight prep: bf16, de-interleaved, FRAGMENT-ORDERED (coalesced 1KB loads).
//  WqF [3 which][kk4][n8][lane][8]   (e = n*16+lr, k = kk*32+lg*8+j)
//  WpF [kk4][n8][lane][8]
//  W1F [c16][kk4][n2][lane][8]       (col = c*32+n*16+lr, k = kk*32+lg*8+j)
//  W2F [c16][n8][lane][8]            (col = n*16+lr, k = c*32+lg*8+j)
// ---------------------------------------------------------------------------
__global__ __launch_bounds__(256) void prep_kernel(
    const float* __restrict__ Wqkv, const float* __restrict__ bqkv,
    const float* __restrict__ Wproj, const float* __restrict__ W1,
    const float* __restrict__ W2,
    u16* __restrict__ WqF, u16* __restrict__ WpF,
    u16* __restrict__ W1F, u16* __restrict__ W2F,
    float* __restrict__ bqp)
{
  const int gid = blockIdx.x * 256 + threadIdx.x;
  if (gid < 73728) {
    const int d = gid / 24576, g = gid % 24576;
    if (g < 6144) {                       // qkv
      const int which = g >> 11, r = g & 2047;
      const int kk = r >> 9, n = (r >> 6) & 7, lane = r & 63;
      const int lr = lane & 15, lg = lane >> 4;
      const int e = (n << 4) + lr;
      u16* dst = WqF + d * 49152 + which * 16384 + (((kk << 3) + n) << 9) + (lane << 3);
      const float* src = Wqkv + (size_t)d * 49152;
#pragma unroll
      for (int j = 0; j < 8; ++j)
        dst[j] = f2bf(src[(size_t)((kk << 5) + (lg << 3) + j) * 384 + e * 3 + which]);
    } else if (g < 8192) {                // proj
      const int r = g - 6144;
      const int kk = r >> 9, n = (r >> 6) & 7, lane = r & 63;
      const int lr = lane & 15, lg = lane >> 4;
      const int col = (n << 4) + lr;
      u16* dst = WpF + d * 16384 + (((kk << 3) + n) << 9) + (lane << 3);
      const float* src = Wproj + (size_t)d * 16384;
#pragma unroll
      for (int j = 0; j < 8; ++j)
        dst[j] = f2bf(src[(size_t)((kk << 5) + (lg << 3) + j) * 128 + col]);
    } else if (g < 16384) {               // W1 [16c][4kk][2n]
      const int r3 = g - 8192;
      const int c = r3 >> 9, kk = (r3 >> 7) & 3, n = (r3 >> 6) & 1, lane = r3 & 63;
      const int lr = lane & 15, lg = lane >> 4;
      const int col = (c << 5) + (n << 4) + lr;
      u16* dst = W1F + d * 65536 + ((((c << 2) + kk) << 1) + n) * 512 + (lane << 3);
      const float* src = W1 + (size_t)d * 65536;
#pragma unroll
      for (int j = 0; j < 8; ++j)
        dst[j] = f2bf(src[(size_t)((kk << 5) + (lg << 3) + j) * 512 + col]);
    } else {                              // W2 [16c][8n]
      const int r4 = g - 16384;
      const int c = r4 >> 9, n = (r4 >> 6) & 7, lane = r4 & 63;
      const int lr = lane & 15, lg = lane >> 4;
      const int col = (n << 4) + lr;
      u16* dst = W2F + d * 65536 + ((c << 3) + n) * 512 + (lane << 3);
      const float* src = W2 + (size_t)d * 65536;
#pragma unroll
      for (int j = 0; j < 8; ++j)
        dst[j] = f2bf(src[(size_t)((c << 5) + (lg << 3) + j) * 128 + col]);
    }
  } else if (gid < 73728 + 1152) {
    const int i2 = gid - 73728; const int d = i2 / 384, c = i2 % 384;
    bqp[i2] = bqkv[d * 384 + (c & 127) * 3 + (c >> 7)];
  }
}

// ---------------------------------------------------------------------------
// img [128][131072] f32 -> x2 HEAD-MAJOR [4096 h][32 z][128] f32 + LN1 stats.
// ---------------------------------------------------------------------------
__global__ __launch_bounds__(256) void tin_kernel(const float* __restrict__ img,
                                                  float* __restrict__ x2,
                                                  float* __restrict__ partials,
                                                  int prow0)
{
  __shared__ float t[128 * 65];
  __shared__ float ssum[256], sqq[256];
  const int t0 = blockIdx.x * 64;
  const int z = t0 >> 12, h0 = t0 & 4095;
  const int tid = threadIdx.x;
  {
    const int j = tid & 63, cq = tid >> 6;
    for (int c = cq; c < 128; c += 4) t[c * 65 + j] = img[(size_t)c * N_TOK + t0 + j];
  }
  __syncthreads();
  {
    const int c = tid & 127, jh = tid >> 7;
    float s = 0.f, q = 0.f;
    for (int jj = jh; jj < 64; jj += 2) {
      const float v = t[c * 65 + jj];
      x2[(size_t)((h0 + jj) * 32 + z) * 128 + c] = v;
      s += v; q += v * v;
    }
    ssum[tid] = s; sqq[tid] = q;
  }
  __syncthreads();
  if (tid < 128) {
    float* pr = partials + (size_t)(prow0 + blockIdx.x) * 256;
    pr[tid] = ssum[tid] + ssum[tid + 128];
    pr[128 + tid] = sqq[tid] + sqq[tid + 128];
  }
}

// x2 head-major -> out [128][131072] with relu
__global__ __launch_bounds__(256) void tout_kernel(const float* __restrict__ x2,
                                                   float* __restrict__ out)
{
  __shared__ float t[128 * 65];
  const int t0 = blockIdx.x * 64;
  const int z = t0 >> 12, h0 = t0 & 4095;
  const int tid = threadIdx.x;
  {
    const int c = tid & 127, jh = tid >> 7;
    for (int jj = jh; jj < 64; jj += 2)
      t[c * 65 + jj] = x2[(size_t)((h0 + jj) * 32 + z) * 128 + c];
  }
  __syncthreads();
  {
    const int j = tid & 63, cq = tid >> 6;
    for (int c = cq; c < 128; c += 4)
      out[(size_t)c * N_TOK + t0 + j] = fmaxf(t[c * 65 + j], 0.f);
  }
}

// stage-1 reduce
__global__ __launch_bounds__(256) void reduce1_kernel(const float* __restrict__ p,
                                                      int rows0, int nrows,
                                                      float* __restrict__ bred)
{
  const int chunk = nrows >> 6;
  const float* base = p + (size_t)(rows0 + blockIdx.x * chunk) * 256;
  float s = 0.f;
  for (int r = 0; r < chunk; ++r) s += base[r * 256 + threadIdx.x];
  bred[blockIdx.x * 256 + threadIdx.x] = s;
}

__global__ void finalize_kernel(const float* __restrict__ bred, const float* __restrict__ g,
                                const float* __restrict__ b, float* __restrict__ st)
{
  const int c = threadIdx.x;   // 128
  float s = 0.f, q = 0.f;
  for (int r = 0; r < 64; ++r) { s += bred[r * 256 + c]; q += bred[r * 256 + 128 + c]; }
  const float inv = 1.f / 131072.f;
  const float mu = s * inv;
  const float var = q * inv - mu * mu;
  const float sc = g[c] * rsqrtf(var + 1e-5f);
  st[c] = sc;
  st[128 + c] = b[c] - mu * sc;
}

// ---------------------------------------------------------------------------
// Device helpers
// ---------------------------------------------------------------------------
__device__ __forceinline__ void ln_load_afrags(const float* __restrict__ x0,
                                               const float* __restrict__ x1,
                                               const float* __restrict__ st,
                                               int lg, bf16x8 aF[2][4]) {
#pragma unroll
  for (int kk = 0; kk < 4; ++kk) {
    const int k0 = (kk << 5) + (lg << 3);
    const fvec4 sA = *(const fvec4*)(st + k0);
    const fvec4 sB = *(const fvec4*)(st + k0 + 4);
    const fvec4 tA = *(const fvec4*)(st + 128 + k0);
    const fvec4 tB = *(const fvec4*)(st + 128 + k0 + 4);
    {
      const fvec4 v0 = *(const fvec4*)(x0 + k0);
      const fvec4 v1 = *(const fvec4*)(x0 + k0 + 4);
      u32x4 w;
      w[0] = cvtpk(v0[0] * sA[0] + tA[0], v0[1] * sA[1] + tA[1]);
      w[1] = cvtpk(v0[2] * sA[2] + tA[2], v0[3] * sA[3] + tA[3]);
      w[2] = cvtpk(v1[0] * sB[0] + tB[0], v1[1] * sB[1] + tB[1]);
      w[3] = cvtpk(v1[2] * sB[2] + tB[2], v1[3] * sB[3] + tB[3]);
      aF[0][kk] = __builtin_bit_cast(bf16x8, w);
    }
    {
      const fvec4 v0 = *(const fvec4*)(x1 + k0);
      const fvec4 v1 = *(const fvec4*)(x1 + k0 + 4);
      u32x4 w;
      w[0] = cvtpk(v0[0] * sA[0] + tA[0], v0[1] * sA[1] + tA[1]);
      w[1] = cvtpk(v0[2] * sA[2] + tA[2], v0[3] * sA[3] + tA[3]);
      w[2] = cvtpk(v1[0] * sB[0] + tB[0], v1[1] * sB[1] + tB[1]);
      w[3] = cvtpk(v1[2] * sB[2] + tB[2], v1[3] * sB[3] + tB[3]);
      aF[1][kk] = __builtin_bit_cast(bf16x8, w);
    }
  }
}

// acc[2][8] = Aregs @ B, B from FRAGMENT-ORDERED buffer (coalesced 1KB loads)
__device__ __forceinline__ void gemm_rA_fB8(const bf16x8 aF[2][4], const u16* __restrict__ F,
                                            int lane, f32x4 acc[2][8]) {
#pragma unroll
  for (int mt = 0; mt < 2; ++mt)
#pragma unroll
    for (int n = 0; n < 8; ++n) acc[mt][n] = (f32x4){0.f, 0.f, 0.f, 0.f};
#pragma unroll
  for (int kk = 0; kk < 4; ++kk) {
    bf16x8 bfr[8];
#pragma unroll
    for (int n = 0; n < 8; ++n)
      bfr[n] = *(const bf16x8*)&F[((((kk << 3) + n) << 9)) + (lane << 3)];
#pragma unroll
    for (int mt = 0; mt < 2; ++mt)
#pragma unroll
      for (int n = 0; n < 8; ++n)
        acc[mt][n] = mfma16(aF[mt][kk], bfr[n], acc[mt][n]);
  }
}

// epilogue: acc (32 rows x 128 cols) -> LDS transpose -> coalesced residual RMW
// + per-col stats. Wave-private.
__device__ __forceinline__ void epi(const f32x4 acc[2][8], float* __restrict__ fb,
                                    float* __restrict__ xr, const float* __restrict__ bias,
                                    float* __restrict__ pr, int lr, int lg) {
#pragma unroll
  for (int ch = 0; ch < 2; ++ch) {
#pragma unroll
    for (int n = 0; n < 4; ++n) {
      const int cl = (n << 4) + lr;
      const float bb = bias[(ch << 6) + cl];
#pragma unroll
      for (int mt = 0; mt < 2; ++mt)
#pragma unroll
        for (int rr = 0; rr < 4; ++rr)
          fb[((mt << 4) + (lg << 2) + rr) * 65 + cl] = acc[mt][(ch << 2) + n][rr] + bb;
    }
    float s0 = 0, s1 = 0, s2 = 0, s3 = 0, q0 = 0, q1 = 0, q2 = 0, q3 = 0;
#pragma unroll
    for (int i = 0; i < 8; ++i) {
      const int row = (i << 2) + lg;
      const int cb = lr << 2;
      const float v0 = fb[row * 65 + cb + 0];
      const float v1 = fb[row * 65 + cb + 1];
      const float v2 = fb[row * 65 + cb + 2];
      const float v3 = fb[row * 65 + cb + 3];
      float* gx = xr + row * 128 + (ch << 6) + cb;
      fvec4 g = *(const fvec4*)gx;
      g[0] += v0; g[1] += v1; g[2] += v2; g[3] += v3;
      *(fvec4*)gx = g;
      s0 += g[0]; q0 += g[0] * g[0];
      s1 += g[1]; q1 += g[1] * g[1];
      s2 += g[2]; q2 += g[2] * g[2];
      s3 += g[3]; q3 += g[3] * g[3];
    }
    s0 += __shfl_xor(s0, 16); s0 += __shfl_xor(s0, 32);
    s1 += __shfl_xor(s1, 16); s1 += __shfl_xor(s1, 32);
    s2 += __shfl_xor(s2, 16); s2 += __shfl_xor(s2, 32);
    s3 += __shfl_xor(s3, 16); s3 += __shfl_xor(s3, 32);
    q0 += __shfl_xor(q0, 16); q0 += __shfl_xor(q0, 32);
    q1 += __shfl_xor(q1, 16); q1 += __shfl_xor(q1, 32);
    q2 += __shfl_xor(q2, 16); q2 += __shfl_xor(q2, 32);
    q3 += __shfl_xor(q3, 16); q3 += __shfl_xor(q3, 32);
    if (lg == 0) {
      *(fvec4*)&pr[(ch << 6) + (lr << 2)] = (fvec4){s0, s1, s2, s3};
      *(fvec4*)&pr[128 + (ch << 6) + (lr << 2)] = (fvec4){q0, q1, q2, q3};
    }
  }
}

// ---------------------------------------------------------------------------
// Wave-private fused attention: 1 wave = 1 head, head-major x2. (unchanged)
// ---------------------------------------------------------------------------
__global__ __launch_bounds__(128) void attn_fused_kernel(
    const u16* __restrict__ WF,           // frag-ordered [3][16384]
    const float* __restrict__ bqp,        // [384]
    const u16* __restrict__ WpF,          // frag-ordered [16384]
    const float* __restrict__ bprj,       // [128]
    const float* __restrict__ st,         // [256] LN1 fold
    float* __restrict__ partials,
    float* __restrict__ x2)               // head-major [4096*32][128]
{
  __shared__ u16 lds[2][2][4096];
  const int tid = threadIdx.x;
  const int lane = tid & 63, wave = tid >> 6;
  const int lr = lane & 15, lg = lane >> 4;
  const int head = (blockIdx.x << 1) + wave;
  u16* RK = &lds[wave][0][0];
  u16* RQ = &lds[wave][1][0];
  float* xh = x2 + ((size_t)head << 12);

  bf16x8 aF[2][4];
  ln_load_afrags(xh + (lr << 7), xh + ((lr + 16) << 7), st, lg, aF);

  // K -> RK, Q -> RQ
  {
    f32x4 kacc[2][8];
    gemm_rA_fB8(aF, WF + 16384, lane, kacc);
#pragma unroll
    for (int n = 0; n < 8; ++n) {
      const int el = (n << 4) + lr;
      const float bb = bqp[128 + el];
#pragma unroll
      for (int mt = 0; mt < 2; ++mt)
#pragma unroll
        for (int rr = 0; rr < 4; ++rr)
          RK[tix((mt << 4) + (lg << 2) + rr, el)] = f2bf(kacc[mt][n][rr] + bb);
    }
  }
  {
    f32x4 qacc[2][8];
    gemm_rA_fB8(aF, WF, lane, qacc);
#pragma unroll
    for (int n = 0; n < 8; ++n) {
      const int el = (n << 4) + lr;
      const float bb = bqp[el];
#pragma unroll
      for (int mt = 0; mt < 2; ++mt)
#pragma unroll
        for (int rr = 0; rr < 4; ++rr)
          RQ[tix((mt << 4) + (lg << 2) + rr, el)] = f2bf(qacc[mt][n][rr] + bb);
    }
  }

  // E^T = K @ Q^T
  f32x4 et[2][2];
#pragma unroll
  for (int mt = 0; mt < 2; ++mt)
#pragma unroll
    for (int nt = 0; nt < 2; ++nt) et[mt][nt] = (f32x4){0.f, 0.f, 0.f, 0.f};
#pragma unroll
  for (int kt = 0; kt < 4; ++kt) {
    const int ks = (kt << 5) + (lg << 3);
    bf16x8 ka[2], qb2[2];
#pragma unroll
    for (int t = 0; t < 2; ++t) {
      ka[t]  = *(const bf16x8*)&RK[tix((t << 4) + lr, ks)];
      qb2[t] = *(const bf16x8*)&RQ[tix((t << 4) + lr, ks)];
    }
#pragma unroll
    for (int mt = 0; mt < 2; ++mt)
#pragma unroll
      for (int nt = 0; nt < 2; ++nt)
        et[mt][nt] = mfma16(ka[mt], qb2[nt], et[mt][nt]);
  }

  // softmax over kz, /sqrt(128), *cm (verified math)
  float p[2][2][4];
#pragma unroll
  for (int nt = 0; nt < 2; ++nt) {
    float mx = -1e30f;
#pragma unroll
    for (int mt = 0; mt < 2; ++mt)
#pragma unroll
      for (int r = 0; r < 4; ++r) mx = fmaxf(mx, et[mt][nt][r]);
    mx = fmaxf(mx, __shfl_xor(mx, 16));
    mx = fmaxf(mx, __shfl_xor(mx, 32));
    float s = 0.f;
#pragma unroll
    for (int mt = 0; mt < 2; ++mt)
#pragma unroll
      for (int r = 0; r < 4; ++r) {
        const float e = __expf(et[mt][nt][r] - mx);
        p[mt][nt][r] = e;
        s += e;
      }
    s += __shfl_xor(s, 16);
    s += __shfl_xor(s, 32);
    const float inv = 1.f / (s * 11.313708498984761f);
    const int qz = (nt << 4) + lr;
#pragma unroll
    for (int mt = 0; mt < 2; ++mt)
#pragma unroll
      for (int r = 0; r < 4; ++r) {
        const int kz = (mt << 4) + (lg << 2) + r;
        const float d = (float)(kz - qz);
        p[mt][nt][r] *= inv * __expf(d * d * (-1.f / 16.f));
      }
  }

  // P^T -> attL (RK head region)
#pragma unroll
  for (int nt = 0; nt < 2; ++nt) {
    const int q = (nt << 4) + lr;
    const int qs = (q >> 1) & 3;
#pragma unroll
    for (int mt = 0; mt < 2; ++mt) {
      const int hc = (mt << 2) + lg;
      const int ch = (hc >> 1) ^ qs;
      const u32 lo = cvtpk(p[mt][nt][0], p[mt][nt][1]);
      const u32 hi = cvtpk(p[mt][nt][2], p[mt][nt][3]);
      *(u64*)&RK[(q << 5) + (ch << 3) + ((hc & 1) << 2)] = (u64)lo | ((u64)hi << 32);
    }
  }
  bf16x8 pa[2];
#pragma unroll
  for (int mt = 0; mt < 2; ++mt) {
    const int q = (mt << 4) + lr;
    pa[mt] = *(const bf16x8*)&RK[(q << 5) + ((lg ^ ((q >> 1) & 3)) << 3)];
  }

  // V -> vT in RQ
  {
    f32x4 vacc[2][8];
    gemm_rA_fB8(aF, WF + 32768, lane, vacc);
#pragma unroll
    for (int n = 0; n < 8; ++n) {
      const int el = (n << 4) + lr;
      const float bb = bqp[256 + el];
#pragma unroll
      for (int mt = 0; mt < 2; ++mt)
#pragma unroll
        for (int rr = 0; rr < 4; ++rr) {
          const int kz = (mt << 4) + (lg << 2) + rr;
          RQ[(el << 5) + (((kz >> 3) ^ (el & 3)) << 3) + (kz & 7)] = f2bf(vacc[mt][n][rr] + bb);
        }
    }
  }

  // PV -> aout (RK)
#pragma unroll
  for (int n = 0; n < 8; ++n) {
    const int el = (n << 4) + lr;
    const bf16x8 vb = *(const bf16x8*)&RQ[(el << 5) + ((lg ^ (el & 3)) << 3)];
    const f32x4 z4 = (f32x4){0.f, 0.f, 0.f, 0.f};
    const f32x4 o0 = mfma16(pa[0], vb, z4);
    const f32x4 o1 = mfma16(pa[1], vb, z4);
#pragma unroll
    for (int rr = 0; rr < 4; ++rr) {
      const int q0 = (lg << 2) + rr;
      RK[tix(q0, el)] = f2bf(o0[rr]);
      RK[tix(q0 + 16, el)] = f2bf(o1[rr]);
    }
  }

  // proj: aout @ Wp
  f32x4 pacc[2][8];
#pragma unroll
  for (int mt = 0; mt < 2; ++mt)
#pragma unroll
    for (int n = 0; n < 8; ++n) pacc[mt][n] = (f32x4){0.f, 0.f, 0.f, 0.f};
#pragma unroll
  for (int kk = 0; kk < 4; ++kk) {
    const int ks = (kk << 5) + (lg << 3);
    bf16x8 af[2], bfr[8];
#pragma unroll
    for (int n = 0; n < 8; ++n)
      bfr[n] = *(const bf16x8*)&WpF[(((kk << 3) + n) << 9) + (lane << 3)];
#pragma unroll
    for (int mt = 0; mt < 2; ++mt)
      af[mt] = *(const bf16x8*)&RK[tix((mt << 4) + lr, ks)];
#pragma unroll
    for (int mt = 0; mt < 2; ++mt)
#pragma unroll
      for (int n = 0; n < 8; ++n)
        pacc[mt][n] = mfma16(af[mt], bfr[n], pacc[mt][n]);
  }

  epi(pacc, (float*)&lds[wave][0][0], xh, bprj,
      partials + (size_t)((blockIdx.x << 1) + wave) * 256, lr, lg);
}

// ---------------------------------------------------------------------------
// Wave-private fused FFN: wave owns 64 rows (2x arithmetic intensity per
// weight load: 4 MFMA / 1KB frag). 16 chunks x 32 h-cols. No barriers.
// ---------------------------------------------------------------------------
__global__ __launch_bounds__(256, 2) void ffn_fused_kernel(
    const u16* __restrict__ W1F,    // [16 c][4 kk][2 n][64][8]
    const float* __restrict__ b1,   // [512]
    const u16* __restrict__ W2F,    // [16 c][8 n][64][8]
    const float* __restrict__ b2,   // [128]
    const float* __restrict__ st,   // [256] LN2 fold
    float* __restrict__ partials,
    float* __restrict__ x2)
{
  __shared__ u16 LHall[4][2048];     // per-wave h chunk [64][32]
  __shared__ float fball[4][2112];   // per-wave epilogue transpose
  const int tid = threadIdx.x;
  const int lane = tid & 63, wave = tid >> 6;
  const int lr = lane & 15, lg = lane >> 4;
  const int r0 = (blockIdx.x << 8) + (wave << 6);    // 64 rows/wave
  u16* LH = &LHall[wave][0];
  float* xr = x2 + ((size_t)r0 << 7);

  bf16x8 aF[4][4];
  ln_load_afrags(xr + (lr << 7), xr + ((lr + 16) << 7), st, lg, &aF[0]);
  ln_load_afrags(xr + ((lr + 32) << 7), xr + ((lr + 48) << 7), st, lg, &aF[2]);

  f32x4 acc2[4][8];
#pragma unroll
  for (int mt = 0; mt < 4; ++mt)
#pragma unroll
    for (int n = 0; n < 8; ++n) acc2[mt][n] = (f32x4){0.f, 0.f, 0.f, 0.f};

#pragma unroll 1
  for (int c = 0; c < 16; ++c) {
    // gemm1: a1[64 rows][32 cols] = A @ W1c
    const u16* F1c = W1F + (c << 12);
    f32x4 a1[4][2];
#pragma unroll
    for (int mt = 0; mt < 4; ++mt)
#pragma unroll
      for (int n = 0; n < 2; ++n) a1[mt][n] = (f32x4){0.f, 0.f, 0.f, 0.f};
#pragma unroll
    for (int kk = 0; kk < 4; ++kk) {
      bf16x8 bfr[2];
#pragma unroll
      for (int n = 0; n < 2; ++n)
        bfr[n] = *(const bf16x8*)&F1c[(((kk << 1) + n) << 9) + (lane << 3)];
#pragma unroll
      for (int mt = 0; mt < 4; ++mt)
#pragma unroll
        for (int n = 0; n < 2; ++n)
          a1[mt][n] = mfma16(aF[mt][kk], bfr[n], a1[mt][n]);
    }
    // h = hswish(a1 + b1) -> LH (own-wave rows; in-order DS)
    const float* bb1 = b1 + (c << 5);
#pragma unroll
    for (int n = 0; n < 2; ++n) {
      const int hl = (n << 4) + lr;
      const float bb = bb1[hl];
#pragma unroll
      for (int mt = 0; mt < 4; ++mt)
#pragma unroll
        for (int rr = 0; rr < 4; ++rr) {
          const int rl = (mt << 4) + (lg << 2) + rr;
          const float h = a1[mt][n][rr] + bb;
          const float r6 = fminf(fmaxf(h + 3.f, 0.f), 6.f);
          LH[lh32(rl, hl)] = f2bf(h * r6 * (1.f / 6.f));
        }
    }
    // gemm2: acc2 += LH(k=32) @ W2c
    const u16* F2c = W2F + (c << 12);
    bf16x8 b2f[8];
#pragma unroll
    for (int n = 0; n < 8; ++n)
      b2f[n] = *(const bf16x8*)&F2c[(n << 9) + (lane << 3)];
    bf16x8 af2[4];
#pragma unroll
    for (int mt = 0; mt < 4; ++mt)
      af2[mt] = *(const bf16x8*)&LH[lh32((mt << 4) + lr, lg << 3)];
#pragma unroll
    for (int mt = 0; mt < 4; ++mt)
#pragma unroll
      for (int n = 0; n < 8; ++n)
        acc2[mt][n] = mfma16(af2[mt], b2f[n], acc2[mt][n]);
  }

  const int pbase = (blockIdx.x << 3) + (wave << 1);
  epi(&acc2[0], &fball[wave][0], xr, b2,
      partials + (size_t)pbase * 256, lr, lg);
  epi(&acc2[2], &fball[wave][0], xr + 4096, b2,
      partials + (size_t)(pbase + 1) * 256, lr, lg);
}

// ---------------------------------------------------------------------------
extern "C" void kernel_launch(void* const* d_in, const int* in_sizes, int n_in,
                              void* d_out, int out_size, void* d_ws, size_t ws_size,
                              hipStream_t stream)
{
  const float* img   = (const float*)d_in[0];
  const float* ln1g  = (const float*)d_in[1];
  const float* ln1b  = (const float*)d_in[2];
  const float* Wqkv  = (const float*)d_in[3];
  const float* bqkv  = (const float*)d_in[4];
  const float* Wproj = (const float*)d_in[5];
  const float* bproj = (const float*)d_in[6];
  const float* ln2g  = (const float*)d_in[7];
  const float* ln2b  = (const float*)d_in[8];
  const float* W1    = (const float*)d_in[9];
  const float* b1    = (const float*)d_in[10];
  const float* W2    = (const float*)d_in[11];
  const float* b2    = (const float*)d_in[12];

  char* ws = (char*)d_ws;
  float* x2 = (float*)ws;                             // 64 MB head-major
  char* wsw = ws + ((size_t)64 << 20);
  u16* WqF = (u16*)wsw;                               // 3*49152
  u16* WpF = WqF + 3 * 49152;                         // 3*16384
  u16* W1F = WpF + 3 * 16384;                         // 3*65536
  u16* W2F = W1F + 3 * 65536;                         // 3*65536
  float* bqp = (float*)(W2F + 3 * 65536);             // 3*384
  float* S   = bqp + 3 * 384;                         // 7*256 fold params
  float* bred = S + 7 * 256;                          // 64*256
  float* partials = bred + 64 * 256;                  // 6144*256

  prep_kernel<<<293, 256, 0, stream>>>(Wqkv, bqkv, Wproj, W1, W2, WqF, WpF, W1F, W2F, bqp);
  tin_kernel<<<2048, 256, 0, stream>>>(img, x2, partials, 4096);
  reduce1_kernel<<<64, 256, 0, stream>>>(partials, 4096, 2048, bred);
  finalize_kernel<<<1, 128, 0, stream>>>(bred, ln1g, ln1b, S);

  for (int d = 0; d < 3; ++d) {
    float* st1 = S + (2 * d) * 256;
    float* st2 = S + (2 * d + 1) * 256;
    attn_fused_kernel<<<2048, 128, 0, stream>>>(
        WqF + d * 49152, bqp + d * 384, WpF + d * 16384, bproj + d * 128,
        st1, partials, x2);
    reduce1_kernel<<<64, 256, 0, stream>>>(partials, 0, 4096, bred);
    finalize_kernel<<<1, 128, 0, stream>>>(bred, ln2g + d * 128, ln2b + d * 128, st2);
    ffn_fused_kernel<<<512, 256, 0, stream>>>(
        W1F + d * 65536, b1 + d * 512, W2F + d * 65536, b2 + d * 128,
        st2, partials, x2);
    if (d < 2) {
      reduce1_kernel<<<64, 256, 0, stream>>>(partials, 0, 4096, bred);
      finalize_kernel<<<1, 128, 0, stream>>>(bred, ln1g + (d + 1) * 128, ln1b + (d + 1) * 128,
                                             S + (2 * d + 2) * 256);
    }
  }

  tout_kernel<<<2048, 256, 0, stream>>>(x2, (float*)d_out);
}